// Round 3
// baseline (242.926 us; speedup 1.0000x reference)
//
#include <hip/hip_runtime.h>
#include <math.h>

// QClassifier fused kernel — ROUND-3 MEASUREMENT PROBE:
// identical math to round 2, but the main kernel is launched TWICE
// (idempotent: same inputs -> same outputs rewritten). The headline
// dur_us delta vs round 2 measures the kernel's marginal duration,
// since the kernel itself is invisible in top-5 rocprof rows (all
// harness fills at ~77 us dominate). Revert to single launch next round.
//
// Math reductions vs reference (unchanged, verified passing):
//  - RZ phases are unit-modulus -> cannot affect |state|^2. Dropped.
//  - RY is orthogonal -> probs_k = (V x)_k^2 / ||x||^2; 1/||x||^2 folded into MLP.
//  - Z/ZZ signs are Walsh functions -> one 16-pt FWHT gives all 10 features.

#define PAD 20  // floats per staged sample (16 + 4 pad) -> conflict-free ds_read_b128

__global__ __launch_bounds__(256) void qc_fused(
    const float* __restrict__ x, const float* __restrict__ uw,
    const float* __restrict__ w1, const float* __restrict__ b1,
    const float* __restrict__ w2, const float* __restrict__ b2,
    float* __restrict__ out, int batch)
{
    __shared__ float sX[256 * PAD];   // 20.0 KiB staged samples
    __shared__ float sW1t[160];       // sW1t[f*16 + j] = w1[j*10 + f]
    __shared__ float sB1[16];
    __shared__ float sW2[32];
    __shared__ float sB2[2];
    __shared__ float sCS[8];          // cos(th_q/2), sin(th_q/2)

    const int t = threadIdx.x;

    if (t < 4) {
        float th = 0.5f * uw[2 * t];  // phi column provably irrelevant
        sCS[t]     = cosf(th);
        sCS[4 + t] = sinf(th);
    }
    if (t < 160) sW1t[t] = w1[(t & 15) * 10 + (t >> 4)];
    if (t < 16)  sB1[t] = b1[t];
    if (t < 32)  sW2[t] = w2[t];
    if (t < 2)   sB2[t] = b2[t];

    const float4* xv4 = (const float4*)x;
    const long nv4 = (long)batch * 4;
    const long base4 = (long)blockIdx.x * 1024;
#pragma unroll
    for (int r2 = 0; r2 < 4; ++r2) {
        int f = t + 256 * r2;
        long g = base4 + f;
        float4 v = (g < nv4) ? xv4[g] : make_float4(0.f, 0.f, 0.f, 0.f);
        ((float4*)(sX + (f >> 2) * PAD))[f & 3] = v;
    }
    __syncthreads();

    const float* myx = sX + t * PAD;
    float y[16];
#pragma unroll
    for (int i = 0; i < 4; ++i) {
        float4 v = ((const float4*)myx)[i];
        y[4 * i + 0] = v.x; y[4 * i + 1] = v.y;
        y[4 * i + 2] = v.z; y[4 * i + 3] = v.w;
    }

    float ss = 0.f;
#pragma unroll
    for (int i = 0; i < 16; ++i) ss = fmaf(y[i], y[i], ss);
    const float rn = 1.0f / ss;

#pragma unroll
    for (int q = 0; q < 4; ++q) {
        const float cq = sCS[q], sq = sCS[4 + q];
        const int st = 8 >> q;
#pragma unroll
        for (int i = 0; i < 16; ++i) {
            if ((i & st) == 0) {
                float a = y[i], b = y[i + st];
                y[i]      = fmaf(cq, a, -sq * b);
                y[i + st] = fmaf(sq, a,  cq * b);
            }
        }
    }

    float p[16];
#pragma unroll
    for (int i = 0; i < 16; ++i) p[i] = y[i] * y[i];
#pragma unroll
    for (int st = 1; st < 16; st <<= 1) {
#pragma unroll
        for (int i = 0; i < 16; ++i) {
            if ((i & st) == 0) {
                float a = p[i], b = p[i + st];
                p[i]      = a + b;
                p[i + st] = a - b;
            }
        }
    }

    constexpr int bmap[10] = {8, 4, 2, 1, 12, 10, 9, 6, 5, 3};

    float tacc[16];
#pragma unroll
    for (int j = 0; j < 16; ++j) tacc[j] = 0.f;
#pragma unroll
    for (int f = 0; f < 10; ++f) {
        const float ff = p[bmap[f]];
        const float* col = sW1t + f * 16;
#pragma unroll
        for (int j = 0; j < 16; ++j) tacc[j] = fmaf(col[j], ff, tacc[j]);
    }

    float o0 = sB2[0], o1 = sB2[1];
#pragma unroll
    for (int j = 0; j < 16; ++j) {
        float h = fmaf(tacc[j], rn, sB1[j]);
        h = fmaxf(h, 0.f);
        o0 = fmaf(sW2[j],      h, o0);
        o1 = fmaf(sW2[16 + j], h, o1);
    }

    const long sidx = (long)blockIdx.x * 256 + t;
    if (sidx < batch) ((float2*)out)[sidx] = make_float2(o0, o1);
}

extern "C" void kernel_launch(void* const* d_in, const int* in_sizes, int n_in,
                              void* d_out, int out_size, void* d_ws, size_t ws_size,
                              hipStream_t stream) {
    const float* x  = (const float*)d_in[0];
    const float* uw = (const float*)d_in[1];
    const float* w1 = (const float*)d_in[2];
    const float* b1 = (const float*)d_in[3];
    const float* w2 = (const float*)d_in[4];
    const float* b2 = (const float*)d_in[5];
    float* out = (float*)d_out;

    int batch = in_sizes[0] / 16;
    int blocks = (batch + 255) / 256;
    // PROBE: two identical idempotent launches; headline delta vs round 2
    // == marginal kernel time (second pass partially L3-warm).
    hipLaunchKernelGGL(qc_fused, dim3(blocks), dim3(256), 0, stream,
                       x, uw, w1, b1, w2, b2, out, batch);
    hipLaunchKernelGGL(qc_fused, dim3(blocks), dim3(256), 0, stream,
                       x, uw, w1, b1, w2, b2, out, batch);
}

// Round 4
// 208.259 us; speedup vs baseline: 1.1665x; 1.1665x over previous
//
#include <hip/hip_runtime.h>
#include <math.h>

// QClassifier fused kernel, round 4.
// Math (verified passing since R1):
//  - RZ phases are unit-modulus -> cannot affect |state|^2. Dropped.
//  - RY is orthogonal -> probs_k = (V x)_k^2 / ||x||^2; 1/||x||^2 folded into MLP.
//  - Z/ZZ signs are Walsh functions -> 16-pt FWHT of y^2 gives all 10 features;
//    Walsh coeff 0 == ||x||^2, so no separate norm pass.
// Structure (R4):
//  - 2 samples per thread, lockstep, loads issued upfront.
//  - NO LDS except 8 cos/sin values: weights/biases read with uniform constant
//    indices -> compiler emits s_load (scalar pipe / K$), zero VALU/LDS cost.
//    (R1 vs R2 showed SMEM weights beat LDS-broadcast weights; R3 probe showed
//    the kernel is issue-bound at ~34us vs 21us HBM floor.)

__global__ __launch_bounds__(256) void qc_fused(
    const float* __restrict__ x, const float* __restrict__ uw,
    const float* __restrict__ w1, const float* __restrict__ b1,
    const float* __restrict__ w2, const float* __restrict__ b2,
    float* __restrict__ out, long batch)
{
    __shared__ float sCS[8];
    const int t = threadIdx.x;
    if (t < 8) {
        int q = t & 3;
        float th = 0.5f * uw[2 * q];      // phi column provably irrelevant
        sCS[t] = (t < 4) ? cosf(th) : sinf(th);
    }
    __syncthreads();

    const long base = (long)blockIdx.x * 512 + t;   // sample A; sample B = base+256
    const float4* __restrict__ xv = (const float4*)x;

    float y[2][16];
#pragma unroll
    for (int u = 0; u < 2; ++u) {
        const long s = base + 256 * u;
        if (s < batch) {
#pragma unroll
            for (int i = 0; i < 4; ++i) {
                float4 v = xv[s * 4 + i];
                y[u][4 * i + 0] = v.x; y[u][4 * i + 1] = v.y;
                y[u][4 * i + 2] = v.z; y[u][4 * i + 3] = v.w;
            }
        } else {
#pragma unroll
            for (int i = 0; i < 16; ++i) y[u][i] = (i == 0) ? 1.f : 0.f; // safe dummy
        }
    }

    float cs[4], sn[4];
#pragma unroll
    for (int q = 0; q < 4; ++q) { cs[q] = sCS[q]; sn[q] = sCS[4 + q]; }

    // 4 rounds of RY 2x2 rotations; qubit q acts on bit (3-q) (wire0 = MSB)
#pragma unroll
    for (int q = 0; q < 4; ++q) {
        const int st = 8 >> q;
#pragma unroll
        for (int i = 0; i < 16; ++i) {
            if ((i & st) == 0) {
#pragma unroll
                for (int u = 0; u < 2; ++u) {
                    float a = y[u][i], b = y[u][i + st];
                    y[u][i]      = fmaf(cs[q], a, -sn[q] * b);
                    y[u][i + st] = fmaf(sn[q], a,  cs[q] * b);
                }
            }
        }
    }

    // squares then in-place FWHT (compiler DCEs the 5 unused Walsh outputs)
    float p[2][16];
#pragma unroll
    for (int u = 0; u < 2; ++u)
#pragma unroll
        for (int i = 0; i < 16; ++i) p[u][i] = y[u][i] * y[u][i];
#pragma unroll
    for (int st = 1; st < 16; st <<= 1) {
#pragma unroll
        for (int i = 0; i < 16; ++i) {
            if ((i & st) == 0) {
#pragma unroll
                for (int u = 0; u < 2; ++u) {
                    float a = p[u][i], b = p[u][i + st];
                    p[u][i]      = a + b;
                    p[u][i + st] = a - b;
                }
            }
        }
    }

    const float rn0 = 1.0f / p[0][0];   // p[.][0] = sum(x^2) = ||x||^2
    const float rn1 = 1.0f / p[1][0];

    // features: z0..z3 -> Walsh masks 8,4,2,1 ; zz(i<j) -> 12,10,9,6,5,3
    constexpr int bmap[10] = {8, 4, 2, 1, 12, 10, 9, 6, 5, 3};

    float tacc[2][16];
#pragma unroll
    for (int j = 0; j < 16; ++j) { tacc[0][j] = 0.f; tacc[1][j] = 0.f; }
#pragma unroll
    for (int f = 0; f < 10; ++f) {
        const float pa = p[0][bmap[f]];
        const float pb = p[1][bmap[f]];
#pragma unroll
        for (int j = 0; j < 16; ++j) {
            const float wv = w1[j * 10 + f];      // uniform -> s_load (K$)
            tacc[0][j] = fmaf(wv, pa, tacc[0][j]);
            tacc[1][j] = fmaf(wv, pb, tacc[1][j]);
        }
    }

    float o00 = b2[0], o01 = b2[1];   // sample A outputs
    float o10 = b2[0], o11 = b2[1];   // sample B outputs
#pragma unroll
    for (int j = 0; j < 16; ++j) {
        const float bb  = b1[j];              // uniform -> s_load
        const float w20 = w2[j];
        const float w21 = w2[16 + j];
        float ha = fmaxf(fmaf(tacc[0][j], rn0, bb), 0.f);
        float hb = fmaxf(fmaf(tacc[1][j], rn1, bb), 0.f);
        o00 = fmaf(w20, ha, o00);  o01 = fmaf(w21, ha, o01);
        o10 = fmaf(w20, hb, o10);  o11 = fmaf(w21, hb, o11);
    }

    float2* __restrict__ o2 = (float2*)out;
    if (base < batch)       o2[base]       = make_float2(o00, o01);
    if (base + 256 < batch) o2[base + 256] = make_float2(o10, o11);
}

extern "C" void kernel_launch(void* const* d_in, const int* in_sizes, int n_in,
                              void* d_out, int out_size, void* d_ws, size_t ws_size,
                              hipStream_t stream) {
    const float* x  = (const float*)d_in[0];
    const float* uw = (const float*)d_in[1];
    const float* w1 = (const float*)d_in[2];
    const float* b1 = (const float*)d_in[3];
    const float* w2 = (const float*)d_in[4];
    const float* b2 = (const float*)d_in[5];
    float* out = (float*)d_out;

    long batch = (long)(in_sizes[0] / 16);
    long blocks = (batch + 511) / 512;
    hipLaunchKernelGGL(qc_fused, dim3((unsigned)blocks), dim3(256), 0, stream,
                       x, uw, w1, b1, w2, b2, out, batch);
}

// Round 5
// 203.502 us; speedup vs baseline: 1.1937x; 1.0234x over previous
//
#include <hip/hip_runtime.h>
#include <math.h>

// QClassifier fused kernel, round 5 — hybrid of R2 and R4.
// Math (verified passing since R1):
//  - RZ phases are unit-modulus -> cannot affect |state|^2. Dropped.
//  - RY is orthogonal -> probs_k = (V x)_k^2 / ||x||^2; 1/||x||^2 folded into MLP.
//  - Z/ZZ signs are Walsh functions -> 16-pt FWHT of y^2 gives all 10 features;
//    Walsh coeff 0 == ||x||^2, so no separate norm pass.
// Structure (R5):
//  - Coalesced lane-consecutive float4 global loads staged through LDS
//    (R2-style transpose; 16 cache lines/instr vs 64 for R4's strided loads),
//    but ONLY 8 DS instrs/thread (4x ds_write_b128 + 4x ds_read_b128, PAD=20
//    -> conflict-free) — no LDS weight broadcasts.
//  - Weights/biases via compile-time-uniform indices -> s_load on the scalar
//    pipe (R4-style), zero VALU/DS cost.
//  - 1 sample/thread: low VGPR -> high occupancy for latency hiding.

#define PAD 20  // floats per staged sample: stride 20 -> 8 consecutive lanes'
                // b128 reads tile all 32 banks exactly; 2-way over 16 lanes = free

__global__ __launch_bounds__(256) void qc_fused(
    const float* __restrict__ x, const float* __restrict__ uw,
    const float* __restrict__ w1, const float* __restrict__ b1,
    const float* __restrict__ w2, const float* __restrict__ b2,
    float* __restrict__ out, long batch)
{
    __shared__ float sX[256 * PAD];   // 20.0 KiB
    __shared__ float sCS[8];

    const int t = threadIdx.x;
    if (t < 8) {
        int q = t & 3;
        float th = 0.5f * uw[2 * q];  // phi column provably irrelevant
        sCS[t] = (t < 4) ? cosf(th) : sinf(th);
    }

    // ---- coalesced stage: 256 samples = 1024 float4, lane-consecutive ----
    const float4* __restrict__ xv4 = (const float4*)x;
    const long nv4 = (long)batch * 4;
    const long base4 = (long)blockIdx.x * 1024;
    if (base4 + 1024 <= nv4) {        // uniform branch: full tile, no lane guards
#pragma unroll
        for (int r = 0; r < 4; ++r) {
            int f = t + 256 * r;
            float4 v = xv4[base4 + f];
            ((float4*)(sX + (f >> 2) * PAD))[f & 3] = v;
        }
    } else {
#pragma unroll
        for (int r = 0; r < 4; ++r) {
            int f = t + 256 * r;
            long g = base4 + f;
            float4 v = (g < nv4) ? xv4[g] : make_float4(1.f, 0.f, 0.f, 0.f);
            ((float4*)(sX + (f >> 2) * PAD))[f & 3] = v;
        }
    }
    __syncthreads();

    // ---- per-thread sample readback (4x ds_read_b128, conflict-free) ----
    const float* myx = sX + t * PAD;
    float y[16];
#pragma unroll
    for (int i = 0; i < 4; ++i) {
        float4 v = ((const float4*)myx)[i];
        y[4 * i + 0] = v.x; y[4 * i + 1] = v.y;
        y[4 * i + 2] = v.z; y[4 * i + 3] = v.w;
    }

    float cs[4], sn[4];
#pragma unroll
    for (int q = 0; q < 4; ++q) { cs[q] = sCS[q]; sn[q] = sCS[4 + q]; }

    // 4 rounds of RY 2x2 rotations; qubit q acts on bit (3-q) (wire0 = MSB)
#pragma unroll
    for (int q = 0; q < 4; ++q) {
        const int st = 8 >> q;
#pragma unroll
        for (int i = 0; i < 16; ++i) {
            if ((i & st) == 0) {
                float a = y[i], b = y[i + st];
                y[i]      = fmaf(cs[q], a, -sn[q] * b);
                y[i + st] = fmaf(sn[q], a,  cs[q] * b);
            }
        }
    }

    // squares then in-place FWHT (unused Walsh outputs DCE'd by compiler)
    float p[16];
#pragma unroll
    for (int i = 0; i < 16; ++i) p[i] = y[i] * y[i];
#pragma unroll
    for (int st = 1; st < 16; st <<= 1) {
#pragma unroll
        for (int i = 0; i < 16; ++i) {
            if ((i & st) == 0) {
                float a = p[i], b = p[i + st];
                p[i]      = a + b;
                p[i + st] = a - b;
            }
        }
    }

    const float rn = 1.0f / p[0];     // p[0] = ||x||^2

    // features: z0..z3 -> Walsh masks 8,4,2,1 ; zz(i<j) -> 12,10,9,6,5,3
    constexpr int bmap[10] = {8, 4, 2, 1, 12, 10, 9, 6, 5, 3};

    float tacc[16];
#pragma unroll
    for (int j = 0; j < 16; ++j) tacc[j] = 0.f;
#pragma unroll
    for (int f = 0; f < 10; ++f) {
        const float pf = p[bmap[f]];
#pragma unroll
        for (int j = 0; j < 16; ++j)
            tacc[j] = fmaf(w1[j * 10 + f], pf, tacc[j]);   // uniform -> s_load
    }

    float o0 = b2[0], o1 = b2[1];
#pragma unroll
    for (int j = 0; j < 16; ++j) {
        float h = fmaxf(fmaf(tacc[j], rn, b1[j]), 0.f);    // uniform -> s_load
        o0 = fmaf(w2[j],      h, o0);
        o1 = fmaf(w2[16 + j], h, o1);
    }

    const long sidx = (long)blockIdx.x * 256 + t;
    if (sidx < batch) ((float2*)out)[sidx] = make_float2(o0, o1);
}

extern "C" void kernel_launch(void* const* d_in, const int* in_sizes, int n_in,
                              void* d_out, int out_size, void* d_ws, size_t ws_size,
                              hipStream_t stream) {
    const float* x  = (const float*)d_in[0];
    const float* uw = (const float*)d_in[1];
    const float* w1 = (const float*)d_in[2];
    const float* b1 = (const float*)d_in[3];
    const float* w2 = (const float*)d_in[4];
    const float* b2 = (const float*)d_in[5];
    float* out = (float*)d_out;

    long batch = (long)(in_sizes[0] / 16);
    long blocks = (batch + 255) / 256;
    hipLaunchKernelGGL(qc_fused, dim3((unsigned)blocks), dim3(256), 0, stream,
                       x, uw, w1, b1, w2, b2, out, batch);
}